// Round 1
// baseline (49.670 us; speedup 1.0000x reference)
//
#include <hip/hip_runtime.h>
#include <hip/hip_bf16.h>

// NT-Xent loss, fused flash-LSE over sim = z z^T / T, bf16 MFMA.
// z = concat(z_i, z_j): [8192][128]. Output: scalar mean loss.

#define N_TOT 8192
#define B_HALF 4096
#define DIM 128
#define SPLITS 8
#define COLS_PER_SPLIT (N_TOT / SPLITS) // 1024
#define CHUNK 64                        // cols staged per iteration
#define SCALE_LOG2 20.609929155556627f  // log2(e)/0.07
#define LN2F 0.6931471805599453f

typedef __attribute__((ext_vector_type(8))) short bf16x8;
typedef __attribute__((ext_vector_type(4))) float f32x4;

__device__ __forceinline__ unsigned short f2bf_rne(float f) {
    unsigned int u = __float_as_uint(f);
    u += 0x7FFFu + ((u >> 16) & 1u);
    return (unsigned short)(u >> 16);
}

// ---- kernel 1: convert z_i,z_j f32 -> z bf16 [8192][128] ----
__global__ void convert_kernel(const float* __restrict__ zi,
                               const float* __restrict__ zj,
                               unsigned short* __restrict__ z) {
    int t = blockIdx.x * 256 + threadIdx.x;   // 0..262143, 4 floats each
    int idx = t * 4;
    const float* src = (idx < B_HALF * DIM) ? (zi + idx) : (zj + (idx - B_HALF * DIM));
    float4 v = *(const float4*)src;
    ushort4 o;
    o.x = f2bf_rne(v.x);
    o.y = f2bf_rne(v.y);
    o.z = f2bf_rne(v.z);
    o.w = f2bf_rne(v.w);
    *(ushort4*)(z + idx) = o;
}

// ---- kernel 2: main fused GEMM + online LSE ----
// grid: 128 row-blocks * SPLITS col-splits. block: 256 threads (4 waves).
// wave w owns rows rb*64 + w*16 .. +16; scans cols [sb*1024, sb*1024+1024).
__global__ __launch_bounds__(256) void ntxent_main(
        const unsigned short* __restrict__ z,
        float* __restrict__ Wm, float* __restrict__ Ws, float* __restrict__ Wp) {
    __shared__ bf16x8 lds8[16 * 64]; // [kchunk 0..15][col 0..63] of 8 bf16 = 16 KB

    int bid = blockIdx.x;
    int rb = bid / SPLITS;  // row block 0..127
    int sb = bid % SPLITS;  // col split 0..7
    int tid = threadIdx.x;
    int w = tid >> 6;
    int l = tid & 63;
    int lo = l & 15;        // low lane nibble
    int hi = l >> 4;        // 0..3

    int row = rb * 64 + w * 16 + lo;
    int partner = row ^ B_HALF;

    // B fragments: this wave's 16 rows, full K=128 (16 VGPR-quads)
    bf16x8 bfrag[4];
    const unsigned short* zrow = z + row * DIM + hi * 8;
#pragma unroll
    for (int ks = 0; ks < 4; ++ks)
        bfrag[ks] = *(const bf16x8*)(zrow + ks * 32);

    float m = -INFINITY, s = 0.f, pos = -INFINITY;

    int c_begin = sb * COLS_PER_SPLIT;
    for (int cc = 0; cc < COLS_PER_SPLIT / CHUNK; ++cc) {
        int cbase = c_begin + cc * CHUNK;
        // stage 64 cols x 128 k into LDS, layout [kc][c]
        {
            int c = tid >> 2;
            int kc0 = tid & 3;
            const unsigned short* src = z + (cbase + c) * DIM + kc0 * 8;
#pragma unroll
            for (int i = 0; i < 4; ++i) {
                lds8[(kc0 + 4 * i) * 64 + c] = *(const bf16x8*)(src + i * 32);
            }
        }
        __syncthreads();

        int chunkIdx = cbase >> 6;
        bool check = (chunkIdx == rb) || (chunkIdx == (rb ^ 64)); // diag or partner chunk

#pragma unroll
        for (int cs = 0; cs < 4; ++cs) {
            f32x4 acc = {0.f, 0.f, 0.f, 0.f};
#pragma unroll
            for (int ks = 0; ks < 4; ++ks) {
                bf16x8 a = lds8[(hi + 4 * ks) * 64 + cs * 16 + lo];
                acc = __builtin_amdgcn_mfma_f32_16x16x32_bf16(a, bfrag[ks], acc, 0, 0, 0);
            }
            // lane's 4 values: row = `row`, cols = c0..c0+3 (in log2 units)
            float v0 = acc[0] * SCALE_LOG2;
            float v1 = acc[1] * SCALE_LOG2;
            float v2 = acc[2] * SCALE_LOG2;
            float v3 = acc[3] * SCALE_LOG2;
            if (check) {
                int c0 = cbase + cs * 16 + hi * 4;
                if (c0 + 0 == row) v0 = -INFINITY; else if (c0 + 0 == partner) pos = v0;
                if (c0 + 1 == row) v1 = -INFINITY; else if (c0 + 1 == partner) pos = v1;
                if (c0 + 2 == row) v2 = -INFINITY; else if (c0 + 2 == partner) pos = v2;
                if (c0 + 3 == row) v3 = -INFINITY; else if (c0 + 3 == partner) pos = v3;
            }
            float cmax = fmaxf(fmaxf(v0, v1), fmaxf(v2, v3));
            if (cmax > m) {
                s *= __builtin_amdgcn_exp2f(m - cmax);
                m = cmax;
            }
            s += __builtin_amdgcn_exp2f(v0 - m);
            s += __builtin_amdgcn_exp2f(v1 - m);
            s += __builtin_amdgcn_exp2f(v2 - m);
            s += __builtin_amdgcn_exp2f(v3 - m);
        }
        __syncthreads();
    }

    // merge the 4 partner lanes (same row): xor 16 then 32
#pragma unroll
    for (int off = 16; off <= 32; off <<= 1) {
        float m2 = __shfl_xor(m, off);
        float s2 = __shfl_xor(s, off);
        float p2 = __shfl_xor(pos, off);
        float M = fmaxf(m, m2);
        s = s * __builtin_amdgcn_exp2f(m - M) + s2 * __builtin_amdgcn_exp2f(m2 - M);
        m = M;
        pos = fmaxf(pos, p2);
    }

    if (hi == 0) { // lanes 0..15 hold rows rb*64+w*16+lo
        Wm[sb * N_TOT + row] = m;
        Ws[sb * N_TOT + row] = s;
        Wp[sb * N_TOT + row] = pos;
    }
}

// ---- kernel 3: merge splits, compute loss, reduce ----
__global__ void merge_kernel(const float* __restrict__ Wm,
                             const float* __restrict__ Ws,
                             const float* __restrict__ Wp,
                             float* __restrict__ out) {
    int r = blockIdx.x * 256 + threadIdx.x; // 0..8191
    float m = -INFINITY, s = 0.f, p = -INFINITY;
#pragma unroll
    for (int sb = 0; sb < SPLITS; ++sb) {
        float m2 = Wm[sb * N_TOT + r];
        float s2 = Ws[sb * N_TOT + r];
        float p2 = Wp[sb * N_TOT + r];
        float M = fmaxf(m, m2);
        s = s * __builtin_amdgcn_exp2f(m - M) + s2 * __builtin_amdgcn_exp2f(m2 - M);
        m = M;
        p = fmaxf(p, p2);
    }
    // add the extra exp(pos) term (diag was masked; aug row = [pos, neg-row])
    s += __builtin_amdgcn_exp2f(p - m);
    float loss = ((m + __builtin_amdgcn_logf(s)) - p) * LN2F; // back to natural log

    // block reduction: wave shuffle then cross-wave via LDS
#pragma unroll
    for (int off = 32; off >= 1; off >>= 1)
        loss += __shfl_down(loss, off);
    __shared__ float wsum[4];
    if ((threadIdx.x & 63) == 0) wsum[threadIdx.x >> 6] = loss;
    __syncthreads();
    if (threadIdx.x == 0) {
        float t = wsum[0] + wsum[1] + wsum[2] + wsum[3];
        atomicAdd(out, t * (1.0f / (float)N_TOT));
    }
}

extern "C" void kernel_launch(void* const* d_in, const int* in_sizes, int n_in,
                              void* d_out, int out_size, void* d_ws, size_t ws_size,
                              hipStream_t stream) {
    const float* zi = (const float*)d_in[0];
    const float* zj = (const float*)d_in[1];
    float* out = (float*)d_out;

    unsigned short* z = (unsigned short*)d_ws;                     // 8192*128*2 = 2 MB
    float* Wm = (float*)((char*)d_ws + N_TOT * DIM * 2);
    float* Ws = Wm + SPLITS * N_TOT;
    float* Wp = Ws + SPLITS * N_TOT;

    hipMemsetAsync(d_out, 0, sizeof(float), stream);
    convert_kernel<<<(N_TOT * DIM / 4) / 256, 256, 0, stream>>>(zi, zj, z);
    ntxent_main<<<(N_TOT / 64) * SPLITS, 256, 0, stream>>>(z, Wm, Ws, Wp);
    merge_kernel<<<N_TOT / 256, 256, 0, stream>>>(Wm, Ws, Wp, out);
}

// Round 2
// 47.150 us; speedup vs baseline: 1.0534x; 1.0534x over previous
//
#include <hip/hip_runtime.h>
#include <hip/hip_bf16.h>

// NT-Xent loss, fused flash-LSE over sim = z z^T / T, bf16 MFMA.
// z = concat(z_i, z_j): [8192][128], pre-scaled by sqrt(log2e/T) so the MFMA
// output is directly in log2 units. Per wave: 64 rows in registers (4 groups
// of 16), cols streamed through LDS chunks of 64 via global_load_lds DMA,
// one A-read feeds 4 MFMAs.

#define N_TOT 8192
#define B_HALF 4096
#define DIM 128
#define SPLITS 16
#define ROWS_PER_BLOCK 512                 // 8 waves * 64 rows
#define COLS_PER_SPLIT (N_TOT / SPLITS)    // 512
#define CHUNK 64
#define NCHUNK (COLS_PER_SPLIT / CHUNK)    // 8
#define PRESCALE 4.5398159686f             // sqrt(log2(e)/0.07)
#define LN2F 0.6931471805599453f
#define SKIP_MARGIN 40.0f

typedef __attribute__((ext_vector_type(8))) short bf16x8;
typedef __attribute__((ext_vector_type(4))) float f32x4;

__device__ __forceinline__ unsigned short f2bf_rne(float f) {
    unsigned int u = __float_as_uint(f);
    u += 0x7FFFu + ((u >> 16) & 1u);
    return (unsigned short)(u >> 16);
}

__device__ __forceinline__ void gload16(const void* g, void* l) {
    __builtin_amdgcn_global_load_lds(
        (const __attribute__((address_space(1))) unsigned int*)g,
        (__attribute__((address_space(3))) unsigned int*)l, 16, 0, 0);
}

// ---- kernel 1: convert z_i,z_j f32 -> pre-scaled bf16 z [8192][128] ----
__global__ void convert_kernel(const float* __restrict__ zi,
                               const float* __restrict__ zj,
                               unsigned short* __restrict__ z) {
    int t = blockIdx.x * 256 + threadIdx.x;
    int idx = t * 4;
    const float* src = (idx < B_HALF * DIM) ? (zi + idx) : (zj + (idx - B_HALF * DIM));
    float4 v = *(const float4*)src;
    ushort4 o;
    o.x = f2bf_rne(v.x * PRESCALE);
    o.y = f2bf_rne(v.y * PRESCALE);
    o.z = f2bf_rne(v.z * PRESCALE);
    o.w = f2bf_rne(v.w * PRESCALE);
    *(ushort4*)(z + idx) = o;
}

// ---- kernel 2: main fused GEMM + online LSE ----
// grid: 16 row-blocks (512 rows) * 16 col-splits (512 cols). block: 512 thr.
__global__ __launch_bounds__(512, 2) void ntxent_main(
        const unsigned short* __restrict__ z,
        float* __restrict__ Wm, float* __restrict__ Ws, float* __restrict__ Wp) {
    // chunk buffer: slot = cs*256 + ks*64 + hi*16 + lo  (16B units)
    // slot holds z[cbase + cs*16 + lo][k elems (ks*4+hi)*8 .. +8]
    __shared__ bf16x8 lds[2][1024]; // 2 x 16 KB

    const int bid = blockIdx.x;
    const int rb = bid / SPLITS;
    const int sb = bid % SPLITS;
    const int tid = threadIdx.x;
    const int w = tid >> 6;
    const int l = tid & 63;
    const int lo = l & 15;
    const int hi = l >> 4;

    const int rowbase = rb * ROWS_PER_BLOCK + w * 64;
    const int cbase0 = sb * COLS_PER_SPLIT;

    // per-lane global source for DMA staging (ushort units):
    // call A covers slots [w*64, +64): col = cbase + (w>>2)*16 + lo, kc = (w&3)*4 + hi
    // call B (slots 512 + w*64) is exactly +32 cols = +4096 ushorts
    const unsigned short* gp = z + (size_t)(cbase0 + (w >> 2) * 16 + lo) * DIM
                                 + ((w & 3) * 4 + hi) * 8;

    // prologue: stage chunk 0 into buffer 0
    gload16(gp,        &lds[0][w * 64]);
    gload16(gp + 4096, &lds[0][512 + w * 64]);

    // row fragments: 64 rows per wave, 4 groups of 16, K=128
    bf16x8 bfrag[4][4];
#pragma unroll
    for (int rg = 0; rg < 4; ++rg) {
        const unsigned short* zr = z + (size_t)(rowbase + rg * 16 + lo) * DIM + hi * 8;
#pragma unroll
        for (int ks = 0; ks < 4; ++ks)
            bfrag[rg][ks] = *(const bf16x8*)(zr + ks * 32);
    }

    float m[4], s[4], pos[4];
#pragma unroll
    for (int rg = 0; rg < 4; ++rg) { m[rg] = -INFINITY; s[rg] = 0.f; pos[rg] = -INFINITY; }

    const int dchunk = rowbase >> 6;            // wave's 64 rows are chunk-aligned
    const int pchunk = dchunk ^ (B_HALF >> 6);  // partner cols chunk

    asm volatile("s_waitcnt vmcnt(0)" ::: "memory");
    __syncthreads();

    for (int c = 0; c < NCHUNK; ++c) {
        if (c + 1 < NCHUNK) {
            gp += CHUNK * DIM;
            gload16(gp,        &lds[(c + 1) & 1][w * 64]);
            gload16(gp + 4096, &lds[(c + 1) & 1][512 + w * 64]);
        }
        const bf16x8* buf = lds[c & 1];
        const int cb = cbase0 + c * CHUNK;
        const bool check = ((cb >> 6) == dchunk) || ((cb >> 6) == pchunk);

#pragma unroll
        for (int cs = 0; cs < 4; ++cs) {
            bf16x8 a0 = buf[cs * 256 + 0 * 64 + l];
            bf16x8 a1 = buf[cs * 256 + 1 * 64 + l];
            bf16x8 a2 = buf[cs * 256 + 2 * 64 + l];
            bf16x8 a3 = buf[cs * 256 + 3 * 64 + l];
            f32x4 acc[4];
#pragma unroll
            for (int rg = 0; rg < 4; ++rg) acc[rg] = (f32x4){0.f, 0.f, 0.f, 0.f};
#pragma unroll
            for (int rg = 0; rg < 4; ++rg) {
                acc[rg] = __builtin_amdgcn_mfma_f32_16x16x32_bf16(a0, bfrag[rg][0], acc[rg], 0, 0, 0);
                acc[rg] = __builtin_amdgcn_mfma_f32_16x16x32_bf16(a1, bfrag[rg][1], acc[rg], 0, 0, 0);
                acc[rg] = __builtin_amdgcn_mfma_f32_16x16x32_bf16(a2, bfrag[rg][2], acc[rg], 0, 0, 0);
                acc[rg] = __builtin_amdgcn_mfma_f32_16x16x32_bf16(a3, bfrag[rg][3], acc[rg], 0, 0, 0);
            }

            const int c0 = cb + cs * 16 + hi * 4;
#pragma unroll
            for (int rg = 0; rg < 4; ++rg) {
                float v0 = acc[rg][0], v1 = acc[rg][1], v2 = acc[rg][2], v3 = acc[rg][3];
                if (check) {
                    int r = rowbase + rg * 16 + lo;
                    int p = r ^ B_HALF;
                    if (c0 + 0 == r) v0 = -INFINITY; else if (c0 + 0 == p) pos[rg] = v0;
                    if (c0 + 1 == r) v1 = -INFINITY; else if (c0 + 1 == p) pos[rg] = v1;
                    if (c0 + 2 == r) v2 = -INFINITY; else if (c0 + 2 == p) pos[rg] = v2;
                    if (c0 + 3 == r) v3 = -INFINITY; else if (c0 + 3 == p) pos[rg] = v3;
                }
                float cmax = fmaxf(fmaxf(v0, v1), fmaxf(v2, v3));
                // wave-uniform skip: no lane's group can contribute >= 2^-40 rel.
                if (check || !__all(cmax <= m[rg] - SKIP_MARGIN)) {
                    if (cmax > m[rg]) {
                        s[rg] *= __builtin_amdgcn_exp2f(m[rg] - cmax);
                        m[rg] = cmax;
                    }
                    s[rg] += __builtin_amdgcn_exp2f(v0 - m[rg]);
                    s[rg] += __builtin_amdgcn_exp2f(v1 - m[rg]);
                    s[rg] += __builtin_amdgcn_exp2f(v2 - m[rg]);
                    s[rg] += __builtin_amdgcn_exp2f(v3 - m[rg]);
                }
            }
        }
        asm volatile("s_waitcnt vmcnt(0)" ::: "memory");
        __syncthreads();
    }

    // merge 4 partner lanes (same row, hi=0..3): xor 16 then 32
#pragma unroll
    for (int rg = 0; rg < 4; ++rg) {
        float mm = m[rg], ss = s[rg], pp = pos[rg];
#pragma unroll
        for (int off = 16; off <= 32; off <<= 1) {
            float m2 = __shfl_xor(mm, off);
            float s2 = __shfl_xor(ss, off);
            float p2 = __shfl_xor(pp, off);
            float M = fmaxf(mm, m2);
            ss = ss * __builtin_amdgcn_exp2f(mm - M) + s2 * __builtin_amdgcn_exp2f(m2 - M);
            mm = M;
            pp = fmaxf(pp, p2);
        }
        if (hi == 0) {
            int r = rowbase + rg * 16 + lo;
            Wm[sb * N_TOT + r] = mm;
            Ws[sb * N_TOT + r] = ss;
            Wp[sb * N_TOT + r] = pp;
        }
    }
}

// ---- kernel 3: merge splits, compute loss, reduce ----
__global__ void merge_kernel(const float* __restrict__ Wm,
                             const float* __restrict__ Ws,
                             const float* __restrict__ Wp,
                             float* __restrict__ out) {
    int r = blockIdx.x * 256 + threadIdx.x; // 0..8191
    float m = -INFINITY, s = 0.f, p = -INFINITY;
#pragma unroll
    for (int sb = 0; sb < SPLITS; ++sb) {
        float m2 = Wm[sb * N_TOT + r];
        float s2 = Ws[sb * N_TOT + r];
        float p2 = Wp[sb * N_TOT + r];
        float M = fmaxf(m, m2);
        s = s * __builtin_amdgcn_exp2f(m - M) + s2 * __builtin_amdgcn_exp2f(m2 - M);
        m = M;
        p = fmaxf(p, p2);
    }
    // aug row = [pos, neg-row]: add exp(pos) once more
    s += __builtin_amdgcn_exp2f(p - m);
    float loss = ((m + __builtin_amdgcn_logf(s)) - p) * LN2F;

#pragma unroll
    for (int off = 32; off >= 1; off >>= 1)
        loss += __shfl_down(loss, off);
    __shared__ float wsum[4];
    if ((threadIdx.x & 63) == 0) wsum[threadIdx.x >> 6] = loss;
    __syncthreads();
    if (threadIdx.x == 0) {
        float t = wsum[0] + wsum[1] + wsum[2] + wsum[3];
        atomicAdd(out, t * (1.0f / (float)N_TOT));
    }
}

extern "C" void kernel_launch(void* const* d_in, const int* in_sizes, int n_in,
                              void* d_out, int out_size, void* d_ws, size_t ws_size,
                              hipStream_t stream) {
    const float* zi = (const float*)d_in[0];
    const float* zj = (const float*)d_in[1];
    float* out = (float*)d_out;

    unsigned short* z = (unsigned short*)d_ws;                 // 2 MB
    float* Wm = (float*)((char*)d_ws + N_TOT * DIM * 2);
    float* Ws = Wm + SPLITS * N_TOT;
    float* Wp = Ws + SPLITS * N_TOT;

    hipMemsetAsync(d_out, 0, sizeof(float), stream);
    convert_kernel<<<(N_TOT * DIM / 4) / 256, 256, 0, stream>>>(zi, zj, z);
    ntxent_main<<<(N_TOT / ROWS_PER_BLOCK) * SPLITS, 512, 0, stream>>>(z, Wm, Ws, Wp);
    merge_kernel<<<N_TOT / 256, 256, 0, stream>>>(Wm, Ws, Wp, out);
}